// Round 12
// baseline (228.048 us; speedup 1.0000x reference)
//
#include <hip/hip_runtime.h>
#include <math.h>

typedef _Float16 half_t;
typedef __attribute__((ext_vector_type(8))) _Float16 half8;
typedef __attribute__((ext_vector_type(4))) _Float16 half4;
typedef __attribute__((ext_vector_type(2))) _Float16 half2v;
typedef __attribute__((ext_vector_type(4))) float floatx4;

#define BATCH   8
#define SEQ     4096
#define DM      512
#define NP      256
#define M_TOT   32768
#define NTOT    768
#define CHUNKS  256
#define CHUNK_LEN 16

__device__ __forceinline__ void async_load16(const void* g, void* l) {
    __builtin_amdgcn_global_load_lds((const __attribute__((address_space(1))) void*)g,
                                     (__attribute__((address_space(3))) void*)l,
                                     16, 0, 0);
}

// ---------------------------------------------------------------------------
// decay + x fp32->fp16 convert. 2 rows per wave.
// ---------------------------------------------------------------------------
__global__ __launch_bounds__(256) void decay_convert(const float* __restrict__ X,
                                                     const float* __restrict__ Wd,
                                                     const float* __restrict__ bd,
                                                     float* __restrict__ dec,
                                                     half_t* __restrict__ Xh) {
    const int wave = threadIdx.x >> 6;
    const int lane = threadIdx.x & 63;
    const int row0 = blockIdx.x * 8 + wave * 2;
    const float4* x0 = (const float4*)(X + (size_t)row0 * DM);
    const float4* x1 = x0 + 128;
    const float4* wd = (const float4*)Wd;
    float4 a0 = x0[2 * lane], a1 = x0[2 * lane + 1];
    float4 b0 = x1[2 * lane], b1 = x1[2 * lane + 1];
    float4 w0 = wd[2 * lane], w1 = wd[2 * lane + 1];
    float s0 = a0.x * w0.x + a0.y * w0.y + a0.z * w0.z + a0.w * w0.w
             + a1.x * w1.x + a1.y * w1.y + a1.z * w1.z + a1.w * w1.w;
    float s1 = b0.x * w0.x + b0.y * w0.y + b0.z * w0.z + b0.w * w0.w
             + b1.x * w1.x + b1.y * w1.y + b1.z * w1.z + b1.w * w1.w;
    half8 h0 = {(half_t)a0.x, (half_t)a0.y, (half_t)a0.z, (half_t)a0.w,
                (half_t)a1.x, (half_t)a1.y, (half_t)a1.z, (half_t)a1.w};
    half8 h1 = {(half_t)b0.x, (half_t)b0.y, (half_t)b0.z, (half_t)b0.w,
                (half_t)b1.x, (half_t)b1.y, (half_t)b1.z, (half_t)b1.w};
    *(half8*)(Xh + (size_t)row0 * DM + lane * 8) = h0;
    *(half8*)(Xh + (size_t)(row0 + 1) * DM + lane * 8) = h1;
#pragma unroll
    for (int off = 32; off > 0; off >>= 1) {
        s0 += __shfl_down(s0, off, 64);
        s1 += __shfl_down(s1, off, 64);
    }
    if (lane == 0) {
        dec[row0]     = 1.0f / (1.0f + __expf(-(s0 + bd[0])));
        dec[row0 + 1] = 1.0f / (1.0f + __expf(-(s1 + bd[0])));
    }
}

// ---------------------------------------------------------------------------
// Wcat_t[768][512] fp16 = [Wi^T ; Wa^T] — 1536 blocks, 1 elem/thread.
// ---------------------------------------------------------------------------
__global__ __launch_bounds__(256) void wcat_transpose(const float* __restrict__ Wi,
                                                      const float* __restrict__ Wa,
                                                      half_t* __restrict__ Wt) {
    const int idx = blockIdx.x * 256 + threadIdx.x;
    const int n = idx >> 9;
    const int k = idx & 511;
    float v = (n < DM) ? Wi[(size_t)k * DM + n] : Wa[(size_t)k * NP + (n - DM)];
    Wt[idx] = (half_t)v;
}

// ---------------------------------------------------------------------------
// Fused MFMA GEMM — r8 BK=32 K-loop. Outputs:
//   bn<4 : inj written fp32 DIRECTLY to out (r0-proven scattered epilogue)
//   bn>=4: planar (cos,sin) fp16 via r9's LDS-staged swizzled epilogue —
//          sincos computed HERE so the scan is transcendental-free.
// Workspace note: r11 failed (container died 2x) with a 101.6MB layout;
// this revision frees the fp16-inj buffer and ends at 68.0MB (< proven 84.8).
// ---------------------------------------------------------------------------
__global__ __launch_bounds__(256) void gemm_fused(const half_t* __restrict__ Xh,
                                                  const half_t* __restrict__ Wt,
                                                  const float* __restrict__ bi,
                                                  const float* __restrict__ ba,
                                                  float* __restrict__ out,
                                                  half_t* __restrict__ cosb,
                                                  half_t* __restrict__ sinb) {
    __shared__ __align__(16) char As[8192];
    __shared__ __align__(16) char Bs[8192];

    const int bm   = blockIdx.x;
    const int bn   = blockIdx.y;
    const int tid  = threadIdx.x;
    const int wave = tid >> 6;
    const int lane = tid & 63;
    const int quad = lane >> 4;
    const int l16  = lane & 15;
    const int wrow = wave >> 1;
    const int wcol = wave & 1;

    floatx4 acc[4][4];
#pragma unroll
    for (int i = 0; i < 4; ++i)
#pragma unroll
        for (int j = 0; j < 4; ++j) acc[i][j] = (floatx4){0.f, 0.f, 0.f, 0.f};

    const int s0 = wave * 128 + lane;
    const int s1 = s0 + 64;
    const int r0 = s0 >> 2, kql0 = (s0 & 3) ^ ((r0 >> 1) & 3);
    const int r1 = s1 >> 2, kql1 = (s1 & 3) ^ ((r1 >> 1) & 3);
    const half_t* gA0 = Xh + (size_t)(bm * 128 + r0) * DM + kql0 * 8;
    const half_t* gA1 = Xh + (size_t)(bm * 128 + r1) * DM + kql1 * 8;
    const half_t* gB0 = Wt + (size_t)(bn * 128 + r0) * DM + kql0 * 8;
    const half_t* gB1 = Wt + (size_t)(bn * 128 + r1) * DM + kql1 * 8;
    char* lA0 = As + wave * 2048;
    char* lA1 = As + wave * 2048 + 1024;
    char* lB0 = Bs + wave * 2048;
    char* lB1 = Bs + wave * 2048 + 1024;

    for (int k0 = 0; k0 < DM; k0 += 32) {
        async_load16(gA0 + k0, lA0);
        async_load16(gA1 + k0, lA1);
        async_load16(gB0 + k0, lB0);
        async_load16(gB1 + k0, lB1);
        __syncthreads();

        half8 af[4], bf[4];
#pragma unroll
        for (int mt = 0; mt < 4; ++mt) {
            const int r = wrow * 64 + mt * 16 + l16;
            af[mt] = *(const half8*)(As + r * 64 + ((quad ^ ((r >> 1) & 3)) << 4));
        }
#pragma unroll
        for (int nt = 0; nt < 4; ++nt) {
            const int r = wcol * 64 + nt * 16 + l16;
            bf[nt] = *(const half8*)(Bs + r * 64 + ((quad ^ ((r >> 1) & 3)) << 4));
        }
#pragma unroll
        for (int mt = 0; mt < 4; ++mt)
#pragma unroll
            for (int nt = 0; nt < 4; ++nt)
                acc[mt][nt] = __builtin_amdgcn_mfma_f32_16x16x32_f16(af[mt], bf[nt],
                                                                     acc[mt][nt], 0, 0, 0);
        __syncthreads();
    }

    const bool is_inj = (bn < 4);
    if (is_inj) {
        // direct fp32 stores to out (64B segments per quad-row; ~9% ampl.)
        const int colbase = bn * 128 + wcol * 64;
#pragma unroll
        for (int nt = 0; nt < 4; ++nt) {
            const int col = colbase + nt * 16 + l16;
            const float bias = bi[col];
#pragma unroll
            for (int mt = 0; mt < 4; ++mt) {
                const int rowb = bm * 128 + wrow * 64 + mt * 16 + quad * 4;
#pragma unroll
                for (int r = 0; r < 4; ++r)
                    out[(size_t)(rowb + r) * DM + col] = acc[mt][nt][r] + bias;
            }
        }
    } else {
        float bias[4];
#pragma unroll
        for (int nt = 0; nt < 4; ++nt) {
            const int colt = wcol * 64 + nt * 16 + l16;
            bias[nt] = ba[bn * 128 + colt - DM];
        }
        half_t* Cs = (half_t*)As;   // 16 KB = 64 rows x 128 cols fp16
        const int cb = bn * 128 - DM;   // pair-column base (0 or 128)
#pragma unroll
        for (int plane = 0; plane < 2; ++plane) {
            half_t* pd = plane ? sinb : cosb;
#pragma unroll
            for (int rh = 0; rh < 2; ++rh) {
                __syncthreads();
                if (wrow == rh) {
#pragma unroll
                    for (int mt = 0; mt < 4; ++mt)
#pragma unroll
                        for (int nt = 0; nt < 4; ++nt)
#pragma unroll
                            for (int r = 0; r < 4; ++r) {
                                const int lr = mt * 16 + quad * 4 + r;
                                const int lc = wcol * 64 + nt * 16 + l16;
                                const float av = acc[mt][nt][r] + bias[nt];
                                float sv, cv;
                                __sincosf(av, &sv, &cv);
                                Cs[lr * 128 + (lc ^ (((lr >> 2) & 3) << 4))] =
                                    (half_t)(plane ? sv : cv);
                            }
                }
                __syncthreads();
#pragma unroll
                for (int it = 0; it < 4; ++it) {
                    const int idx = it * 256 + tid;
                    const int rr  = idx >> 4;
                    const int cc  = (idx & 15) * 8;
                    const int grow = bm * 128 + rh * 64 + rr;
                    half8 v = *(half8*)(Cs + rr * 128 + (cc ^ (((rr >> 2) & 3) << 4)));
                    *(half8*)(pd + (size_t)grow * NP + cb + cc) = v;
                }
            }
        }
    }
}

// ---------------------------------------------------------------------------
// sum1: per-chunk summaries, transcendental-free (12 FMA/step chain).
// inj read fp32 from out.
// ---------------------------------------------------------------------------
__global__ __launch_bounds__(256) void scan_sum1(const half_t* __restrict__ cosb,
                                                 const half_t* __restrict__ sinb,
                                                 const float* __restrict__ decays,
                                                 const float* __restrict__ injf,
                                                 float4* __restrict__ csC,
                                                 float4* __restrict__ hend,
                                                 float* __restrict__ Dprod) {
    const int b   = blockIdx.x >> 7;
    const int sub = threadIdx.x >> 7;
    const int th  = threadIdx.x & 127;
    const int c   = (blockIdx.x & 127) * 2 + sub;
    const int p0  = th * 2;
    const int t0  = c * CHUNK_LEN;

    const half_t* cp = cosb + (size_t)(b * SEQ + t0) * NP + p0;
    const half_t* sp = sinb + (size_t)(b * SEQ + t0) * NP + p0;
    const float4* up = (const float4*)injf + (size_t)(b * SEQ + t0) * 128 + th;
    const float*  dp = decays + b * SEQ + t0;

    half2v cb[16], sb[16]; float4 u[16]; float d[16];
#pragma unroll
    for (int j = 0; j < 16; ++j) {
        cb[j] = *(const half2v*)(cp + (size_t)j * NP);
        sb[j] = *(const half2v*)(sp + (size_t)j * NP);
        u[j]  = up[(size_t)j * 128];
        d[j]  = dp[j];
    }

    float h0a = 0, h1a = 0, h0b = 0, h1b = 0;
    float CcA = 1.f, SsA = 0.f, CcB = 1.f, SsB = 0.f, dc = 1.f;
#pragma unroll
    for (int j = 0; j < 16; ++j) {
        const float c0 = (float)cb[j][0], c1 = (float)cb[j][1];
        const float s0 = (float)sb[j][0], s1 = (float)sb[j][1];
        const float dd = d[j];
        float n0a = fmaf(dd, c0 * h0a - s0 * h1a, u[j].x);
        float n1a = fmaf(dd, s0 * h0a + c0 * h1a, u[j].y);
        float n0b = fmaf(dd, c1 * h0b - s1 * h1b, u[j].z);
        float n1b = fmaf(dd, s1 * h0b + c1 * h1b, u[j].w);
        h0a = n0a; h1a = n1a; h0b = n0b; h1b = n1b;
        float tCA = c0 * CcA - s0 * SsA, tSA = s0 * CcA + c0 * SsA;
        float tCB = c1 * CcB - s1 * SsB, tSB = s1 * CcB + c1 * SsB;
        CcA = tCA; SsA = tSA; CcB = tCB; SsB = tSB;
        dc *= dd;
    }
    const size_t idx = (size_t)(b * CHUNKS + c) * 128 + th;
    csC[idx]  = make_float4(CcA, SsA, CcB, SsB);
    hend[idx] = make_float4(h0a, h1a, h0b, h1b);
    if (th == 0) Dprod[b * CHUNKS + c] = dc;
}

// ---------------------------------------------------------------------------
// chunk-operator scan — Kogge-Stone, transcendental-free (composes (c,s)).
// ---------------------------------------------------------------------------
__global__ __launch_bounds__(256) void scan_chunks(const float4* __restrict__ csC,
                                                   const float4* __restrict__ hend,
                                                   const float* __restrict__ Dprod,
                                                   float4* __restrict__ hentry) {
    const int b  = blockIdx.x >> 7;
    const int pp = blockIdx.x & 127;
    const int c  = threadIdx.x;

    __shared__ float4 sCS[256];
    __shared__ float4 sV[256];
    __shared__ float  sD[256];

    const size_t idx = (size_t)(b * CHUNKS + c) * 128 + pp;
    float4 cs = csC[idx];
    float4 v  = hend[idx];
    float  D  = Dprod[b * CHUNKS + c];
    sCS[c] = cs; sV[c] = v; sD[c] = D;

#pragma unroll
    for (int o = 1; o < 256; o <<= 1) {
        __syncthreads();
        float4 lcs = make_float4(1.f, 0.f, 1.f, 0.f);
        float4 lv  = make_float4(0.f, 0.f, 0.f, 0.f);
        float  lD  = 0.f;
        const bool has = (c >= o);
        if (has) { lcs = sCS[c - o]; lv = sV[c - o]; lD = sD[c - o]; }
        __syncthreads();
        if (has) {
            v.x = fmaf(D, cs.x * lv.x - cs.y * lv.y, v.x);
            v.y = fmaf(D, cs.y * lv.x + cs.x * lv.y, v.y);
            v.z = fmaf(D, cs.z * lv.z - cs.w * lv.w, v.z);
            v.w = fmaf(D, cs.w * lv.z + cs.z * lv.w, v.w);
            float nx = cs.x * lcs.x - cs.y * lcs.y;
            float ny = cs.y * lcs.x + cs.x * lcs.y;
            float nz = cs.z * lcs.z - cs.w * lcs.w;
            float nw = cs.w * lcs.z + cs.z * lcs.w;
            cs = make_float4(nx, ny, nz, nw);
            D *= lD;
            sCS[c] = cs; sV[c] = v; sD[c] = D;
        }
    }
    __syncthreads();
    hentry[idx] = (c == 0) ? make_float4(0.f, 0.f, 0.f, 0.f) : sV[c - 1];
}

// ---------------------------------------------------------------------------
// final: local scan seeded with entry state, transcendental-free.
// Reads inj fp32 from out, overwrites out in place.
// ---------------------------------------------------------------------------
__global__ __launch_bounds__(256) void scan_final(const half_t* __restrict__ cosb,
                                                  const half_t* __restrict__ sinb,
                                                  const float* __restrict__ decays,
                                                  const float4* __restrict__ hentry,
                                                  float* __restrict__ out) {
    const int b   = blockIdx.x >> 7;
    const int sub = threadIdx.x >> 7;
    const int th  = threadIdx.x & 127;
    const int c   = (blockIdx.x & 127) * 2 + sub;
    const int p0  = th * 2;
    const int t0  = c * CHUNK_LEN;

    const half_t* cp = cosb + (size_t)(b * SEQ + t0) * NP + p0;
    const half_t* sp = sinb + (size_t)(b * SEQ + t0) * NP + p0;
    float4*       op = (float4*)out + (size_t)(b * SEQ + t0) * 128 + th;
    const float*  dp = decays + b * SEQ + t0;

    float4 v = hentry[(size_t)(b * CHUNKS + c) * 128 + th];
    float h0a = v.x, h1a = v.y, h0b = v.z, h1b = v.w;

    half2v cb[16], sb[16]; float4 u[16]; float d[16];
#pragma unroll
    for (int j = 0; j < 16; ++j) {
        cb[j] = *(const half2v*)(cp + (size_t)j * NP);
        sb[j] = *(const half2v*)(sp + (size_t)j * NP);
        u[j]  = op[(size_t)j * 128];
        d[j]  = dp[j];
    }

#pragma unroll
    for (int j = 0; j < 16; ++j) {
        const float c0 = (float)cb[j][0], c1 = (float)cb[j][1];
        const float s0 = (float)sb[j][0], s1 = (float)sb[j][1];
        const float dd = d[j];
        float n0a = fmaf(dd, c0 * h0a - s0 * h1a, u[j].x);
        float n1a = fmaf(dd, s0 * h0a + c0 * h1a, u[j].y);
        float n0b = fmaf(dd, c1 * h0b - s1 * h1b, u[j].z);
        float n1b = fmaf(dd, s1 * h0b + c1 * h1b, u[j].w);
        h0a = n0a; h1a = n1a; h0b = n0b; h1b = n1b;
        op[(size_t)j * 128] = make_float4(h0a, h1a, h0b, h1b);
    }
}

// ---------------------------------------------------------------------------
extern "C" void kernel_launch(void* const* d_in, const int* in_sizes, int n_in,
                              void* d_out, int out_size, void* d_ws, size_t ws_size,
                              hipStream_t stream) {
    const float* x  = (const float*)d_in[0];
    const float* Wa = (const float*)d_in[1];
    const float* ba = (const float*)d_in[2];
    const float* Wd = (const float*)d_in[3];
    const float* bd = (const float*)d_in[4];
    const float* Wi = (const float*)d_in[5];
    const float* bi = (const float*)d_in[6];
    float* out = (float*)d_out;

    char* ws = (char*)d_ws;
    half_t* x_h     = (half_t*)(ws);                  // 33,554,432 B @ 0 (dead after gemm)
    float4* csC     = (float4*)(ws);                  //  4,194,304 B (overlay, post-gemm)
    float4* hend    = (float4*)(ws + 4194304);        //  4,194,304 B (overlay)
    float*  Dprod   = (float*)(ws + 8388608);         //      8,192 B (overlay)
    float4* hentry  = (float4*)(ws + 8396800);        //  4,194,304 B (overlay, ends 12,591,104)
    half_t* cosb    = (half_t*)(ws + 33554432);       // 16,777,216 B
    half_t* sinb    = (half_t*)(ws + 50331648);       // 16,777,216 B
    float*  decays  = (float*)(ws + 67108864);        //    131,072 B
    half_t* Wcat_t  = (half_t*)(ws + 67239936);       //    786,432 B (ends 68,026,368 < 84.8MB proven)

    decay_convert<<<M_TOT / 8, 256, 0, stream>>>(x, Wd, bd, decays, x_h);
    wcat_transpose<<<(NTOT * DM) / 256, 256, 0, stream>>>(Wi, Wa, Wcat_t);
    gemm_fused<<<dim3(M_TOT / 128, NTOT / 128), 256, 0, stream>>>(x_h, Wcat_t, bi, ba,
                                                                  out, cosb, sinb);

    scan_sum1<<<BATCH * CHUNKS / 2, 256, 0, stream>>>(cosb, sinb, decays, out,
                                                      csC, hend, Dprod);
    scan_chunks<<<BATCH * 128, 256, 0, stream>>>(csC, hend, Dprod, hentry);
    scan_final<<<BATCH * CHUNKS / 2, 256, 0, stream>>>(cosb, sinb, decays, hentry, out);
}